// Round 1
// baseline (316.192 us; speedup 1.0000x reference)
//
#include <hip/hip_runtime.h>
#include <cstdint>

// Problem constants
#define EE 512
#define HH 16
#define DD 32
#define LL 2048
#define SS 2048
#define NBATCH 4
#define ROWS 8192   // L*N = S*N
#define LN_EPS 1e-5f

typedef _Float16 f16;
typedef _Float16 half8_t __attribute__((ext_vector_type(8)));
typedef _Float16 half4_t __attribute__((ext_vector_type(4)));
typedef float f32x4 __attribute__((ext_vector_type(4)));

// async global->LDS, 16B per lane; LDS dest = wave-uniform base + lane*16
__device__ __forceinline__ void gl_lds16(const void* g, void* l) {
    __builtin_amdgcn_global_load_lds(
        (__attribute__((address_space(1))) void*)(uintptr_t)g,
        (__attribute__((address_space(3))) void*)(uint32_t)(uintptr_t)l,
        16, 0, 0);
}

// ---------------------------------------------------------------- cast weights
__global__ void k_cast(const float* __restrict__ W1f, const float* __restrict__ W2f,
                       f16* __restrict__ W1h, f16* __restrict__ W2h) {
    int t = blockIdx.x * blockDim.x + threadIdx.x;   // 262144 threads
    const int n1 = (1536 * 512) / 4;                 // 196608 float4 of W1
    const float4* src;
    half4_t* dst;
    int idx;
    if (t < n1) { src = (const float4*)W1f; dst = (half4_t*)W1h; idx = t; }
    else        { src = (const float4*)W2f; dst = (half4_t*)W2h; idx = t - n1; }
    float4 v = src[idx];
    half4_t h;
    h[0] = (f16)v.x; h[1] = (f16)v.y; h[2] = (f16)v.z; h[3] = (f16)v.w;
    dst[idx] = h;
}

// ---------------------------------------------------------------- in-projection
// C = X @ W^T + b ;  X f32 (8192x512), W f16 (1536x512, row=out feature, k-contig)
// grid (64, 12); block col selects section: 0->Q, 1->K, 2->V. Output f16 (8192x512) each.
__global__ __launch_bounds__(256) void k_inproj(
    const float* __restrict__ Xq, const float* __restrict__ Xk, const float* __restrict__ Xv,
    const f16* __restrict__ W1, const float* __restrict__ bias,
    f16* __restrict__ Qb, f16* __restrict__ Kb, f16* __restrict__ Vb)
{
    __shared__ __align__(16) f16 Al[128 * 32];
    __shared__ __align__(16) f16 Bl[128 * 32];

    const int tid = threadIdx.x;
    const int m0 = blockIdx.x * 128;
    const int f0 = blockIdx.y * 128;          // global output-feature base [0,1536)
    const int sec = f0 >> 9;
    const float* X = (sec == 0) ? Xq : ((sec == 1) ? Xk : Xv);
    f16* Ob = (sec == 0) ? Qb : ((sec == 1) ? Kb : Vb);
    const int fl0 = f0 & 511;

    const int wid = tid >> 6, ln = tid & 63, l15 = ln & 15, quad = ln >> 4;
    const int wm = wid >> 1, wn = wid & 1;

    f32x4 z4 = {0.f, 0.f, 0.f, 0.f};
    f32x4 acc[4][4];
    #pragma unroll
    for (int i = 0; i < 4; ++i)
        #pragma unroll
        for (int j = 0; j < 4; ++j) acc[i][j] = z4;

    for (int kt = 0; kt < 16; ++kt) {
        const int k0 = kt * 32;
        // B tile (weights, already f16): async 16B loads, 2 instr/wave
        #pragma unroll
        for (int i = 0; i < 2; ++i) {
            int row = wid * 32 + i * 16 + (ln >> 2);
            gl_lds16(W1 + (size_t)(f0 + row) * 512 + k0 + (ln & 3) * 8,
                     Bl + (wid * 32 + i * 16) * 32);
        }
        // A tile: f32 load + convert + ds_write
        #pragma unroll
        for (int c = 0; c < 4; ++c) {
            int ch = c * 256 + tid;          // 0..1023 chunks of 4 floats
            int row = ch >> 3, q4 = ch & 7;
            float4 v = *(const float4*)(X + (size_t)(m0 + row) * 512 + k0 + q4 * 4);
            half4_t h;
            h[0] = (f16)v.x; h[1] = (f16)v.y; h[2] = (f16)v.z; h[3] = (f16)v.w;
            *(half4_t*)(Al + row * 32 + q4 * 4) = h;
        }
        __syncthreads();

        half8_t a[4], b[4];
        #pragma unroll
        for (int i = 0; i < 4; ++i)
            a[i] = *(const half8_t*)(Al + (wm * 64 + i * 16 + l15) * 32 + quad * 8);
        #pragma unroll
        for (int j = 0; j < 4; ++j)
            b[j] = *(const half8_t*)(Bl + (wn * 64 + j * 16 + l15) * 32 + quad * 8);
        #pragma unroll
        for (int i = 0; i < 4; ++i)
            #pragma unroll
            for (int j = 0; j < 4; ++j)
                acc[i][j] = __builtin_amdgcn_mfma_f32_16x16x32_f16(a[i], b[j], acc[i][j], 0, 0, 0);
        __syncthreads();
    }

    // epilogue: C/D layout col=lane&15, row=quad*4+reg
    #pragma unroll
    for (int i = 0; i < 4; ++i) {
        int row = m0 + wm * 64 + i * 16 + quad * 4;
        #pragma unroll
        for (int j = 0; j < 4; ++j) {
            int col = wn * 64 + j * 16 + l15;
            float bs = bias[f0 + col];
            #pragma unroll
            for (int r = 0; r < 4; ++r)
                Ob[(size_t)(row + r) * 512 + fl0 + col] = (f16)(acc[i][j][r] + bs);
        }
    }
}

// ---------------------------------------------------------------- grouped LayerNorm over D=32
// 8 lanes per group, in place on Kb then Vb (both in one launch).
__global__ void k_norm(f16* __restrict__ Kb, f16* __restrict__ Vb,
                       const float* __restrict__ w, const float* __restrict__ b) {
    int t = blockIdx.x * blockDim.x + threadIdx.x;   // 2,097,152 threads
    int lane8 = t & 7;
    int g = t >> 3;                                  // 262144 groups
    f16* buf = (g < 131072) ? Kb : Vb;
    int g2 = g & 131071;
    int r = g2 >> 4, h = g2 & 15;
    f16* p = buf + (size_t)r * 512 + h * 32 + lane8 * 4;
    half4_t x = *(const half4_t*)p;
    float xf[4];
    #pragma unroll
    for (int j = 0; j < 4; ++j) xf[j] = (float)x[j];
    float s = xf[0] + xf[1] + xf[2] + xf[3];
    float ss = xf[0] * xf[0] + xf[1] * xf[1] + xf[2] * xf[2] + xf[3] * xf[3];
    s  += __shfl_xor(s, 1);  s  += __shfl_xor(s, 2);  s  += __shfl_xor(s, 4);
    ss += __shfl_xor(ss, 1); ss += __shfl_xor(ss, 2); ss += __shfl_xor(ss, 4);
    float mean = s * (1.f / 32.f);
    float var = ss * (1.f / 32.f) - mean * mean;
    float rs = rsqrtf(var + LN_EPS);
    half4_t y;
    #pragma unroll
    for (int j = 0; j < 4; ++j) {
        int d = lane8 * 4 + j;
        y[j] = (f16)((xf[j] - mean) * rs * w[d] + b[d]);
    }
    *(half4_t*)p = y;
}

// ---------------------------------------------------------------- flash attention
// grid (16, 64): x = Q-tile (128 rows of L), y = n*16+h. Block 256 = 4 waves; each
// wave owns 32 Q-rows. S iterated in 128-tiles with online softmax (exp2 domain).
__global__ __launch_bounds__(256) void k_flash(
    const f16* __restrict__ Qb, const f16* __restrict__ Kb, const f16* __restrict__ Vb,
    const float* __restrict__ scaling, f16* __restrict__ Ob)
{
    __shared__ __align__(16) f16 Ql[128 * 32];
    __shared__ __align__(16) f16 Kl[128 * 32];
    __shared__ __align__(16) f16 Vt[32 * 136];       // V^T, padded stride 136
    __shared__ __align__(16) f16 Pl[4][32 * 136];    // per-wave P, padded stride 136

    const int tid = threadIdx.x;
    const int wid = tid >> 6, ln = tid & 63, l15 = ln & 15, quad = ln >> 4;
    const int q0 = blockIdx.x * 128;
    const int h = blockIdx.y & 15, n = blockIdx.y >> 4;
    const float sc = scaling[h] * 1.44269504f;       // beta * log2(e)

    // stage Q tile once
    #pragma unroll
    for (int i = 0; i < 2; ++i) {
        int l = q0 + wid * 32 + i * 16 + (ln >> 2);
        gl_lds16(Qb + ((size_t)l * NBATCH + n) * 512 + h * 32 + (ln & 3) * 8,
                 Ql + (wid * 32 + i * 16) * 32);
    }
    __syncthreads();
    half8_t aq[2];
    #pragma unroll
    for (int i = 0; i < 2; ++i)
        aq[i] = *(const half8_t*)(Ql + (wid * 32 + i * 16 + l15) * 32 + quad * 8);

    f32x4 z4 = {0.f, 0.f, 0.f, 0.f};
    float m_i[2][4], l_i[2][4];
    f32x4 accO[2][2];
    #pragma unroll
    for (int i = 0; i < 2; ++i) {
        #pragma unroll
        for (int r = 0; r < 4; ++r) { m_i[i][r] = -1e30f; l_i[i][r] = 0.f; }
        accO[i][0] = z4; accO[i][1] = z4;
    }

    for (int st = 0; st < 16; ++st) {
        const int s0 = st * 128;
        __syncthreads();   // prior iteration done reading Kl/Vt
        // stage K tile (async)
        #pragma unroll
        for (int i = 0; i < 2; ++i) {
            int s = s0 + wid * 32 + i * 16 + (ln >> 2);
            gl_lds16(Kb + ((size_t)s * NBATCH + n) * 512 + h * 32 + (ln & 3) * 8,
                     Kl + (wid * 32 + i * 16) * 32);
        }
        // stage V transposed: Vt[d][s]
        #pragma unroll
        for (int c2 = 0; c2 < 2; ++c2) {
            int c = c2 * 256 + tid;
            int s = c >> 2, dc = c & 3;
            half8_t vv = *(const half8_t*)(Vb + ((size_t)(s0 + s) * NBATCH + n) * 512 + h * 32 + dc * 8);
            #pragma unroll
            for (int j = 0; j < 8; ++j) Vt[(dc * 8 + j) * 136 + s] = vv[j];
        }
        __syncthreads();

        // scores: S[q][s], one K=32 MFMA per 16x16 tile
        f32x4 accS[2][8];
        #pragma unroll
        for (int ct = 0; ct < 8; ++ct) {
            half8_t bk = *(const half8_t*)(Kl + (ct * 16 + l15) * 32 + quad * 8);
            accS[0][ct] = __builtin_amdgcn_mfma_f32_16x16x32_f16(aq[0], bk, z4, 0, 0, 0);
            accS[1][ct] = __builtin_amdgcn_mfma_f32_16x16x32_f16(aq[1], bk, z4, 0, 0, 0);
        }

        // online softmax; rows live on 16-lane groups (same quad)
        #pragma unroll
        for (int i = 0; i < 2; ++i) {
            float mnew[4], alpha[4], rowsum[4];
            #pragma unroll
            for (int r = 0; r < 4; ++r) {
                float mx = -1e30f;
                #pragma unroll
                for (int ct = 0; ct < 8; ++ct) {
                    accS[i][ct][r] *= sc;
                    mx = fmaxf(mx, accS[i][ct][r]);
                }
                mx = fmaxf(mx, __shfl_xor(mx, 1));
                mx = fmaxf(mx, __shfl_xor(mx, 2));
                mx = fmaxf(mx, __shfl_xor(mx, 4));
                mx = fmaxf(mx, __shfl_xor(mx, 8));
                mnew[r] = fmaxf(m_i[i][r], mx);
                alpha[r] = __builtin_amdgcn_exp2f(m_i[i][r] - mnew[r]);
                rowsum[r] = 0.f;
            }
            #pragma unroll
            for (int ct = 0; ct < 8; ++ct) {
                #pragma unroll
                for (int r = 0; r < 4; ++r) {
                    float pv = __builtin_amdgcn_exp2f(accS[i][ct][r] - mnew[r]);
                    rowsum[r] += pv;
                    // C-layout -> A-layout via LDS (row = q within 32, col = s)
                    Pl[wid][(i * 16 + quad * 4 + r) * 136 + ct * 16 + l15] = (f16)pv;
                }
            }
            #pragma unroll
            for (int r = 0; r < 4; ++r) {
                rowsum[r] += __shfl_xor(rowsum[r], 1);
                rowsum[r] += __shfl_xor(rowsum[r], 2);
                rowsum[r] += __shfl_xor(rowsum[r], 4);
                rowsum[r] += __shfl_xor(rowsum[r], 8);
                l_i[i][r] = l_i[i][r] * alpha[r] + rowsum[r];
                m_i[i][r] = mnew[r];
            }
            #pragma unroll
            for (int dt = 0; dt < 2; ++dt)
                #pragma unroll
                for (int r = 0; r < 4; ++r) accO[i][dt][r] *= alpha[r];
        }

        // PV: O += P @ V   (A = P rows=q k=s; B = V^T rows=d k=s)
        #pragma unroll
        for (int kt = 0; kt < 4; ++kt) {
            half8_t bv[2], ap[2];
            #pragma unroll
            for (int dt = 0; dt < 2; ++dt)
                bv[dt] = *(const half8_t*)(Vt + (dt * 16 + l15) * 136 + kt * 32 + quad * 8);
            #pragma unroll
            for (int i = 0; i < 2; ++i)
                ap[i] = *(const half8_t*)(Pl[wid] + (i * 16 + l15) * 136 + kt * 32 + quad * 8);
            #pragma unroll
            for (int i = 0; i < 2; ++i)
                #pragma unroll
                for (int dt = 0; dt < 2; ++dt)
                    accO[i][dt] = __builtin_amdgcn_mfma_f32_16x16x32_f16(ap[i], bv[dt], accO[i][dt], 0, 0, 0);
        }
    }

    // epilogue: O / l -> f16, layout (l*N+n, h*32+d)
    #pragma unroll
    for (int i = 0; i < 2; ++i) {
        #pragma unroll
        for (int r = 0; r < 4; ++r) {
            int l = q0 + wid * 32 + i * 16 + quad * 4 + r;
            float inv = 1.f / l_i[i][r];
            #pragma unroll
            for (int dt = 0; dt < 2; ++dt)
                Ob[((size_t)l * NBATCH + n) * 512 + h * 32 + dt * 16 + l15] =
                    (f16)(accO[i][dt][r] * inv);
        }
    }
}

// ---------------------------------------------------------------- out-projection
// Out = O @ W2^T + b ; O f16 (8192x512), W2 f16 (512x512), Out f32 (d_out)
__global__ __launch_bounds__(256) void k_outproj(
    const f16* __restrict__ A, const f16* __restrict__ W2,
    const float* __restrict__ bias, float* __restrict__ Out)
{
    __shared__ __align__(16) f16 Al[128 * 32];
    __shared__ __align__(16) f16 Bl[128 * 32];

    const int tid = threadIdx.x;
    const int m0 = blockIdx.x * 128;
    const int f0 = blockIdx.y * 128;
    const int wid = tid >> 6, ln = tid & 63, l15 = ln & 15, quad = ln >> 4;
    const int wm = wid >> 1, wn = wid & 1;

    f32x4 z4 = {0.f, 0.f, 0.f, 0.f};
    f32x4 acc[4][4];
    #pragma unroll
    for (int i = 0; i < 4; ++i)
        #pragma unroll
        for (int j = 0; j < 4; ++j) acc[i][j] = z4;

    for (int kt = 0; kt < 16; ++kt) {
        const int k0 = kt * 32;
        #pragma unroll
        for (int i = 0; i < 2; ++i) {
            int row = wid * 32 + i * 16 + (ln >> 2);
            gl_lds16(A + (size_t)(m0 + row) * 512 + k0 + (ln & 3) * 8,
                     Al + (wid * 32 + i * 16) * 32);
            gl_lds16(W2 + (size_t)(f0 + row) * 512 + k0 + (ln & 3) * 8,
                     Bl + (wid * 32 + i * 16) * 32);
        }
        __syncthreads();

        half8_t a[4], b[4];
        #pragma unroll
        for (int i = 0; i < 4; ++i)
            a[i] = *(const half8_t*)(Al + (wm * 64 + i * 16 + l15) * 32 + quad * 8);
        #pragma unroll
        for (int j = 0; j < 4; ++j)
            b[j] = *(const half8_t*)(Bl + (wn * 64 + j * 16 + l15) * 32 + quad * 8);
        #pragma unroll
        for (int i = 0; i < 4; ++i)
            #pragma unroll
            for (int j = 0; j < 4; ++j)
                acc[i][j] = __builtin_amdgcn_mfma_f32_16x16x32_f16(a[i], b[j], acc[i][j], 0, 0, 0);
        __syncthreads();
    }

    #pragma unroll
    for (int i = 0; i < 4; ++i) {
        int row = m0 + wm * 64 + i * 16 + quad * 4;
        #pragma unroll
        for (int j = 0; j < 4; ++j) {
            int col = wn * 64 + j * 16 + l15;
            float bs = bias[f0 + col];
            #pragma unroll
            for (int r = 0; r < 4; ++r)
                Out[(size_t)(row + r) * 512 + f0 + col] = acc[i][j][r] + bs;
        }
    }
}

// ---------------------------------------------------------------- launch
extern "C" void kernel_launch(void* const* d_in, const int* in_sizes, int n_in,
                              void* d_out, int out_size, void* d_ws, size_t ws_size,
                              hipStream_t stream) {
    const float* query   = (const float*)d_in[0];
    const float* key_in  = (const float*)d_in[1];
    const float* value   = (const float*)d_in[2];
    const float* scaling = (const float*)d_in[3];
    const float* ipw     = (const float*)d_in[4];
    const float* ipb     = (const float*)d_in[5];
    const float* pnw     = (const float*)d_in[6];
    const float* pnb     = (const float*)d_in[7];
    const float* opw     = (const float*)d_in[8];
    const float* opb     = (const float*)d_in[9];
    float* out = (float*)d_out;

    // workspace layout (f16): Qb,Kb,Vb,Ob each 8192*512; W1 1536*512; W2 512*512
    f16* Qb = (f16*)d_ws;
    f16* Kb = Qb + (size_t)ROWS * 512;
    f16* Vb = Kb + (size_t)ROWS * 512;
    f16* Ob = Vb + (size_t)ROWS * 512;
    f16* W1 = Ob + (size_t)ROWS * 512;
    f16* W2 = W1 + (size_t)1536 * 512;
    // total: 35,651,584 bytes

    k_cast<<<1024, 256, 0, stream>>>(ipw, opw, W1, W2);
    k_inproj<<<dim3(64, 12), 256, 0, stream>>>(query, key_in, value, W1, ipb, Qb, Kb, Vb);
    k_norm<<<8192, 256, 0, stream>>>(Kb, Vb, pnw, pnb);
    k_flash<<<dim3(16, 64), 256, 0, stream>>>(Qb, Kb, Vb, scaling, Ob);
    k_outproj<<<dim3(64, 4), 256, 0, stream>>>(Ob, W2, opb, out);
}

// Round 3
// 244.621 us; speedup vs baseline: 1.2926x; 1.2926x over previous
//
#include <hip/hip_runtime.h>
#include <cstdint>

// Problem constants
#define LN_EPS 1e-5f

typedef _Float16 f16;
typedef _Float16 half4_t __attribute__((ext_vector_type(4)));
typedef _Float16 half8_t __attribute__((ext_vector_type(8)));
typedef __fp16 fp16v2 __attribute__((ext_vector_type(2)));
typedef float f32x4 __attribute__((ext_vector_type(4)));

// async global->LDS, 16B per lane; LDS dest = wave-uniform base + lane*16
__device__ __forceinline__ void gl_lds16(const void* g, void* l) {
    __builtin_amdgcn_global_load_lds(
        (__attribute__((address_space(1))) void*)(uintptr_t)g,
        (__attribute__((address_space(3))) void*)(uint32_t)(uintptr_t)l,
        16, 0, 0);
}

// pack 4 floats -> 4 f16 via v_cvt_pkrtz
__device__ __forceinline__ half4_t pack4(float a, float b, float c, float d) {
    fp16v2 lo = __builtin_amdgcn_cvt_pkrtz(a, b);
    fp16v2 hi = __builtin_amdgcn_cvt_pkrtz(c, d);
    half4_t r;
    r[0] = (f16)lo[0]; r[1] = (f16)lo[1]; r[2] = (f16)hi[0]; r[3] = (f16)hi[1];
    return r;
}

// ---------------------------------------------------------------- cast weights
__global__ void k_cast(const float* __restrict__ W1f, const float* __restrict__ W2f,
                       f16* __restrict__ W1h, f16* __restrict__ W2h) {
    int t = blockIdx.x * blockDim.x + threadIdx.x;   // 262144 threads
    const int n1 = (1536 * 512) / 4;                 // 196608 float4 of W1
    const float4* src;
    half4_t* dst;
    int idx;
    if (t < n1) { src = (const float4*)W1f; dst = (half4_t*)W1h; idx = t; }
    else        { src = (const float4*)W2f; dst = (half4_t*)W2h; idx = t - n1; }
    float4 v = src[idx];
    half4_t h;
    h[0] = (f16)v.x; h[1] = (f16)v.y; h[2] = (f16)v.z; h[3] = (f16)v.w;
    dst[idx] = h;
}

// ---------------------------------------------------------------- in-projection
// C = X @ W^T + b ; outputs in chunk-major per-(n,h) layout: T[g][c][len][8],
// g=n*16+h, c=d-chunk (d = c*8+e). Q additionally pre-scaled by beta*log2(e).
__global__ __launch_bounds__(256) void k_inproj(
    const float* __restrict__ Xq, const float* __restrict__ Xk, const float* __restrict__ Xv,
    const f16* __restrict__ W1, const float* __restrict__ bias,
    const float* __restrict__ scaling,
    f16* __restrict__ Qg, f16* __restrict__ Kg, f16* __restrict__ Vg)
{
    __shared__ __align__(16) f16 Al[128 * 32];
    __shared__ __align__(16) f16 Bl[128 * 32];

    const int tid = threadIdx.x;
    const int m0 = blockIdx.x * 128;
    const int f0 = blockIdx.y * 128;          // global output-feature base [0,1536)
    const int sec = f0 >> 9;
    const float* X = (sec == 0) ? Xq : ((sec == 1) ? Xk : Xv);
    f16* Ob = (sec == 0) ? Qg : ((sec == 1) ? Kg : Vg);
    const int fl0 = f0 & 511;

    const int wid = tid >> 6, ln = tid & 63, l15 = ln & 15, quad = ln >> 4;
    const int wm = wid >> 1, wn = wid & 1;

    f32x4 z4 = {0.f, 0.f, 0.f, 0.f};
    f32x4 acc[4][4];
    #pragma unroll
    for (int i = 0; i < 4; ++i)
        #pragma unroll
        for (int j = 0; j < 4; ++j) acc[i][j] = z4;

    for (int kt = 0; kt < 16; ++kt) {
        const int k0 = kt * 32;
        #pragma unroll
        for (int i = 0; i < 2; ++i) {
            int row = wid * 32 + i * 16 + (ln >> 2);
            gl_lds16(W1 + (size_t)(f0 + row) * 512 + k0 + (ln & 3) * 8,
                     Bl + (wid * 32 + i * 16) * 32);
        }
        #pragma unroll
        for (int c = 0; c < 4; ++c) {
            int ch = c * 256 + tid;          // 0..1023 chunks of 4 floats
            int row = ch >> 3, q4 = ch & 7;
            float4 v = *(const float4*)(X + (size_t)(m0 + row) * 512 + k0 + q4 * 4);
            *(half4_t*)(Al + row * 32 + q4 * 4) = pack4(v.x, v.y, v.z, v.w);
        }
        __syncthreads();

        half8_t a[4], b[4];
        #pragma unroll
        for (int i = 0; i < 4; ++i)
            a[i] = *(const half8_t*)(Al + (wm * 64 + i * 16 + l15) * 32 + quad * 8);
        #pragma unroll
        for (int j = 0; j < 4; ++j)
            b[j] = *(const half8_t*)(Bl + (wn * 64 + j * 16 + l15) * 32 + quad * 8);
        #pragma unroll
        for (int i = 0; i < 4; ++i)
            #pragma unroll
            for (int j = 0; j < 4; ++j)
                acc[i][j] = __builtin_amdgcn_mfma_f32_16x16x32_f16(a[i], b[j], acc[i][j], 0, 0, 0);
        __syncthreads();
    }

    // epilogue: C/D layout col=lane&15, row=quad*4+reg; scatter to chunk layout
    #pragma unroll
    for (int i = 0; i < 4; ++i) {
        int row = m0 + wm * 64 + i * 16 + quad * 4;
        #pragma unroll
        for (int j = 0; j < 4; ++j) {
            int col = wn * 64 + j * 16 + l15;
            int f_local = fl0 + col;
            int hh = f_local >> 5, cc = (f_local >> 3) & 3, e = f_local & 7;
            float bs = bias[f0 + col];
            float sc2 = (sec == 0) ? scaling[hh] * 1.44269504f : 1.0f;
            #pragma unroll
            for (int r = 0; r < 4; ++r) {
                int rm = row + r;
                int l = rm >> 2, nb = rm & 3;
                int gg = nb * 16 + hh;
                Ob[(size_t)gg * 65536 + (size_t)cc * 16384 + (size_t)l * 8 + e] =
                    (f16)((acc[i][j][r] + bs) * sc2);
            }
        }
    }
}

// ---------------------------------------------------------------- LayerNorm on K (in place)
// Kg layout [g][c][2048][8]; one thread per (g,s): in-thread LN over 32 d.
__global__ void k_norm_k(f16* __restrict__ Kg, const float* __restrict__ w,
                         const float* __restrict__ b) {
    int t = blockIdx.x * 256 + threadIdx.x;   // 131072
    int g = t >> 11, s = t & 2047;
    f16* base = Kg + (size_t)g * 65536 + (size_t)s * 8;
    half8_t x[4];
    float xf[32], s1 = 0.f, s2 = 0.f;
    #pragma unroll
    for (int c = 0; c < 4; ++c) {
        x[c] = *(const half8_t*)(base + (size_t)c * 16384);
        #pragma unroll
        for (int j = 0; j < 8; ++j) {
            float v = (float)x[c][j];
            xf[c * 8 + j] = v; s1 += v; s2 += v * v;
        }
    }
    float mean = s1 * (1.f / 32.f);
    float var = s2 * (1.f / 32.f) - mean * mean;
    float rs = rsqrtf(var + LN_EPS);
    #pragma unroll
    for (int c = 0; c < 4; ++c) {
        half8_t y;
        #pragma unroll
        for (int j = 0; j < 8; ++j) {
            int d = c * 8 + j;
            y[j] = (f16)((xf[d] - mean) * rs * w[d] + b[d]);
        }
        *(half8_t*)(base + (size_t)c * 16384) = y;
    }
}

// ---------------------------------------------------------------- LayerNorm + transpose on V
// Vg [g][c][2048][8] -> Vtg [g][seg][d=32][c'=8][8] with c' = c_s XOR (d&7)
__global__ void k_norm_vt(const f16* __restrict__ Vg, const float* __restrict__ w,
                          const float* __restrict__ b, f16* __restrict__ Vtg) {
    __shared__ __align__(16) f16 T[32 * 64];   // [d][c'][8]
    const int t = threadIdx.x;
    const int seg = blockIdx.x, g = blockIdx.y;
    const int s_l = t >> 2, c = t & 3;
    half8_t v = *(const half8_t*)(Vg + (size_t)g * 65536 + (size_t)c * 16384 +
                                  (size_t)(seg * 64 + s_l) * 8);
    float xf[8], s1 = 0.f, s2 = 0.f;
    #pragma unroll
    for (int j = 0; j < 8; ++j) { xf[j] = (float)v[j]; s1 += xf[j]; s2 += xf[j] * xf[j]; }
    s1 += __shfl_xor(s1, 1); s1 += __shfl_xor(s1, 2);
    s2 += __shfl_xor(s2, 1); s2 += __shfl_xor(s2, 2);
    float mean = s1 * (1.f / 32.f);
    float var = s2 * (1.f / 32.f) - mean * mean;
    float rs = rsqrtf(var + LN_EPS);
    int cs = s_l >> 3, es = s_l & 7;
    #pragma unroll
    for (int j = 0; j < 8; ++j) {
        int d = c * 8 + j;
        T[d * 64 + (cs ^ j) * 8 + es] = (f16)((xf[j] - mean) * rs * w[d] + b[d]);
    }
    __syncthreads();
    int d_o = t >> 3, c_o = t & 7;
    half8_t out = *(const half8_t*)(T + d_o * 64 + c_o * 8);
    *(half8_t*)(Vtg + (size_t)(g * 32 + seg) * 2048 + d_o * 64 + c_o * 8) = out;
}

// ---------------------------------------------------------------- flash attention
// Transposed-scores design: S^T = K·Q^T (MFMA regs index s), P packed b64 into
// per-wave LDS, V pre-transposed+swizzled. grid (16, 64): x=Q-tile(128), y=g.
// Block 256 = 4 waves; wave owns 32 q. S in 64-wide tiles, online softmax, exp2 domain.
__global__ __launch_bounds__(256, 4) void k_flash(
    const f16* __restrict__ Qg, const f16* __restrict__ Kg,
    const f16* __restrict__ Vtg, f16* __restrict__ Og)
{
    __shared__ __align__(16) char smem[26624];
    f16* Kl = (f16*)smem;                  // [c4][s64][8]  4096 B
    char* VtB = smem + 4096;               // [d32][c'8][8] 4096 B
    char* PlAll = smem + 8192;             // 4 waves x 4608 B (P: 32 rows x 144 B)

    const int tid = threadIdx.x, wid = tid >> 6, ln = tid & 63;
    const int l15 = ln & 15, quad = ln >> 4;
    char* Pw = PlAll + wid * 4608;
    const int g = blockIdx.y, h = g & 15, n = g >> 4;
    const int q0 = blockIdx.x * 128;

    // ---- stage Q once (into Pl region, dead after frag load) ----
    #pragma unroll
    for (int ii = 0; ii < 2; ++ii)
        gl_lds16(Qg + (size_t)g * 65536 + (size_t)wid * 16384 + (size_t)(q0 + ii * 64) * 8 + ln * 8,
                 PlAll + wid * 2048 + ii * 1024);
    __syncthreads();
    half8_t aq[2];
    #pragma unroll
    for (int i = 0; i < 2; ++i)
        aq[i] = *(const half8_t*)(PlAll + quad * 2048 + (wid * 32 + i * 16 + l15) * 16);

    f32x4 z4 = {0.f, 0.f, 0.f, 0.f};
    f32x4 accO[2][2];
    accO[0][0] = z4; accO[0][1] = z4; accO[1][0] = z4; accO[1][1] = z4;
    float m_i[2] = {-1e30f, -1e30f}, l_i[2] = {0.f, 0.f};

    for (int st = 0; st < 32; ++st) {
        __syncthreads();   // prior reads of Kl/Vt done (iter 0: Q-frag reads done)
        gl_lds16(Kg + (size_t)g * 65536 + (size_t)wid * 16384 + (size_t)(st * 64) * 8 + ln * 8,
                 (char*)Kl + wid * 1024);
        gl_lds16(Vtg + (size_t)(g * 32 + st) * 2048 + wid * 512 + ln * 8,
                 VtB + wid * 1024);
        __syncthreads();

        // S^T tile: A = K (m=s), B = Qscaled (n=q); result already in exp2 units
        half8_t ak[4];
        #pragma unroll
        for (int mt = 0; mt < 4; ++mt)
            ak[mt] = *(const half8_t*)((char*)Kl + quad * 1024 + (mt * 16 + l15) * 16);
        f32x4 accS[2][4];
        #pragma unroll
        for (int i = 0; i < 2; ++i)
            #pragma unroll
            for (int mt = 0; mt < 4; ++mt)
                accS[i][mt] = __builtin_amdgcn_mfma_f32_16x16x32_f16(ak[mt], aq[i], z4, 0, 0, 0);

        // online softmax per q (= lane col); cross-lane reduce only over quads
        #pragma unroll
        for (int i = 0; i < 2; ++i) {
            float xmax = accS[i][0][0];
            #pragma unroll
            for (int mt = 0; mt < 4; ++mt)
                #pragma unroll
                for (int r = 0; r < 4; ++r) xmax = fmaxf(xmax, accS[i][mt][r]);
            xmax = fmaxf(xmax, __shfl_xor(xmax, 16));
            xmax = fmaxf(xmax, __shfl_xor(xmax, 32));
            float mnew = fmaxf(m_i[i], xmax);
            float alpha = __builtin_amdgcn_exp2f(m_i[i] - mnew);
            float rs = 0.f;
            #pragma unroll
            for (int mt = 0; mt < 4; ++mt) {
                float p0 = __builtin_amdgcn_exp2f(accS[i][mt][0] - mnew);
                float p1 = __builtin_amdgcn_exp2f(accS[i][mt][1] - mnew);
                float p2 = __builtin_amdgcn_exp2f(accS[i][mt][2] - mnew);
                float p3 = __builtin_amdgcn_exp2f(accS[i][mt][3] - mnew);
                rs += (p0 + p1) + (p2 + p3);
                *(half4_t*)(Pw + (i * 16 + l15) * 144 + mt * 32 + quad * 8) =
                    pack4(p0, p1, p2, p3);
            }
            rs += __shfl_xor(rs, 16);
            rs += __shfl_xor(rs, 32);
            l_i[i] = l_i[i] * alpha + rs;
            m_i[i] = mnew;
            #pragma unroll
            for (int dt = 0; dt < 2; ++dt)
                #pragma unroll
                for (int r = 0; r < 4; ++r) accO[i][dt][r] *= alpha;
        }

        // O^T += V^T · P^T : A = V^T (m=d), B = P^T (n=q)
        #pragma unroll
        for (int kt = 0; kt < 2; ++kt) {
            half8_t av[2], bp[2];
            #pragma unroll
            for (int dt = 0; dt < 2; ++dt) {
                int d = dt * 16 + l15;
                int cp = (kt * 4 + quad) ^ (l15 & 7);
                av[dt] = *(const half8_t*)(VtB + d * 128 + cp * 16);
            }
            #pragma unroll
            for (int i = 0; i < 2; ++i)
                bp[i] = *(const half8_t*)(Pw + (i * 16 + l15) * 144 + kt * 64 + quad * 16);
            #pragma unroll
            for (int i = 0; i < 2; ++i)
                #pragma unroll
                for (int dt = 0; dt < 2; ++dt)
                    accO[i][dt] = __builtin_amdgcn_mfma_f32_16x16x32_f16(av[dt], bp[i], accO[i][dt], 0, 0, 0);
        }
    }

    // epilogue: normalize, transpose via wave-local LDS (stride 40 f16 = 80 B),
    // write Og[n][l][512] coalesced
    #pragma unroll
    for (int i = 0; i < 2; ++i) {
        float inv = 1.f / l_i[i];
        #pragma unroll
        for (int dt = 0; dt < 2; ++dt) {
            *(half4_t*)(Pw + (i * 16 + l15) * 80 + (dt * 16 + quad * 4) * 2) =
                pack4(accO[i][dt][0] * inv, accO[i][dt][1] * inv,
                      accO[i][dt][2] * inv, accO[i][dt][3] * inv);
        }
    }
    int q2 = ln >> 1, hf = ln & 1;
    half8_t o0 = *(const half8_t*)(Pw + q2 * 80 + hf * 32);
    half8_t o1 = *(const half8_t*)(Pw + q2 * 80 + hf * 32 + 16);
    size_t rowe = ((size_t)(n * 2048 + q0 + wid * 32 + q2)) * 512 + h * 32 + hf * 16;
    *(half8_t*)(Og + rowe) = o0;
    *(half8_t*)(Og + rowe + 8) = o1;
}

// ---------------------------------------------------------------- out-projection
// Out = O @ W2^T + b ; O f16 [n][l][512] (rows m = n*2048+l), Out f32 rows l*4+n
__global__ __launch_bounds__(256) void k_outproj(
    const f16* __restrict__ A, const f16* __restrict__ W2,
    const float* __restrict__ bias, float* __restrict__ Out)
{
    __shared__ __align__(16) f16 Al[128 * 32];
    __shared__ __align__(16) f16 Bl[128 * 32];

    const int tid = threadIdx.x;
    const int m0 = blockIdx.x * 128;
    const int f0 = blockIdx.y * 128;
    const int wid = tid >> 6, ln = tid & 63, l15 = ln & 15, quad = ln >> 4;
    const int wm = wid >> 1, wn = wid & 1;

    f32x4 z4 = {0.f, 0.f, 0.f, 0.f};
    f32x4 acc[4][4];
    #pragma unroll
    for (int i = 0; i < 4; ++i)
        #pragma unroll
        for (int j = 0; j < 4; ++j) acc[i][j] = z4;

    for (int kt = 0; kt < 16; ++kt) {
        const int k0 = kt * 32;
        #pragma unroll
        for (int i = 0; i < 2; ++i) {
            int row = wid * 32 + i * 16 + (ln >> 2);
            gl_lds16(A + (size_t)(m0 + row) * 512 + k0 + (ln & 3) * 8,
                     Al + (wid * 32 + i * 16) * 32);
            gl_lds16(W2 + (size_t)(f0 + row) * 512 + k0 + (ln & 3) * 8,
                     Bl + (wid * 32 + i * 16) * 32);
        }
        __syncthreads();

        half8_t a[4], b[4];
        #pragma unroll
        for (int i = 0; i < 4; ++i)
            a[i] = *(const half8_t*)(Al + (wm * 64 + i * 16 + l15) * 32 + quad * 8);
        #pragma unroll
        for (int j = 0; j < 4; ++j)
            b[j] = *(const half8_t*)(Bl + (wn * 64 + j * 16 + l15) * 32 + quad * 8);
        #pragma unroll
        for (int i = 0; i < 4; ++i)
            #pragma unroll
            for (int j = 0; j < 4; ++j)
                acc[i][j] = __builtin_amdgcn_mfma_f32_16x16x32_f16(a[i], b[j], acc[i][j], 0, 0, 0);
        __syncthreads();
    }

    #pragma unroll
    for (int i = 0; i < 4; ++i) {
        int row = m0 + wm * 64 + i * 16 + quad * 4;
        #pragma unroll
        for (int j = 0; j < 4; ++j) {
            int col = wn * 64 + j * 16 + l15;
            float bs = bias[f0 + col];
            #pragma unroll
            for (int r = 0; r < 4; ++r) {
                int rm = row + r;
                int orow = (rm & 2047) * 4 + (rm >> 11);
                Out[(size_t)orow * 512 + f0 + col] = acc[i][j][r] + bs;
            }
        }
    }
}

// ---------------------------------------------------------------- launch
extern "C" void kernel_launch(void* const* d_in, const int* in_sizes, int n_in,
                              void* d_out, int out_size, void* d_ws, size_t ws_size,
                              hipStream_t stream) {
    const float* query   = (const float*)d_in[0];
    const float* key_in  = (const float*)d_in[1];
    const float* value   = (const float*)d_in[2];
    const float* scaling = (const float*)d_in[3];
    const float* ipw     = (const float*)d_in[4];
    const float* ipb     = (const float*)d_in[5];
    const float* pnw     = (const float*)d_in[6];
    const float* pnb     = (const float*)d_in[7];
    const float* opw     = (const float*)d_in[8];
    const float* opb     = (const float*)d_in[9];
    float* out = (float*)d_out;

    // workspace (f16 elements): Qg,Kg,Vg,Vtg each 4,194,304; W1 786,432; W2 262,144
    // Og aliases Vg (Vg fully consumed by k_norm_vt before k_flash writes Og).
    f16* Qg  = (f16*)d_ws;
    f16* Kg  = Qg  + (size_t)4194304;
    f16* Vg  = Kg  + (size_t)4194304;
    f16* Vtg = Vg  + (size_t)4194304;
    f16* W1  = Vtg + (size_t)4194304;
    f16* W2  = W1  + (size_t)786432;
    f16* Og  = Vg;   // alias
    // total: 35,651,584 bytes (same footprint as R1)

    k_cast<<<1024, 256, 0, stream>>>(ipw, opw, W1, W2);
    k_inproj<<<dim3(64, 12), 256, 0, stream>>>(query, key_in, value, W1, ipb, scaling, Qg, Kg, Vg);
    k_norm_k<<<512, 256, 0, stream>>>(Kg, pnw, pnb);
    k_norm_vt<<<dim3(32, 64), 256, 0, stream>>>(Vg, pnw, pnb, Vtg);
    k_flash<<<dim3(16, 64), 256, 0, stream>>>(Qg, Kg, Vtg, Og);
    k_outproj<<<dim3(64, 4), 256, 0, stream>>>(Og, W2, opb, out);
}